// Round 4
// baseline (589.006 us; speedup 1.0000x reference)
//
#include <hip/hip_runtime.h>

typedef __bf16 bf16x8 __attribute__((ext_vector_type(8)));
typedef float f32x4 __attribute__((ext_vector_type(4)));

#define T_LEN 200
#define NB 4096

__device__ __forceinline__ f32x4 mfma16(bf16x8 a, bf16x8 b, f32x4 c) {
    return __builtin_amdgcn_mfma_f32_16x16x32_bf16(a, b, c, 0, 0, 0);
}
__device__ __forceinline__ float sigf(float x) { return 1.0f / (1.0f + __expf(-x)); }
__device__ __forceinline__ float tanh_fast(float x) {
    x = fminf(15.0f, fmaxf(-15.0f, x));
    float e = __expf(2.0f * x);
    return (e - 1.0f) / (e + 1.0f);
}

// bf16 hi/lo split fragment (fp32-accurate MFMA inputs)
struct Frag { bf16x8 hi, lo; };

__device__ __forceinline__ Frag make_frag(f32x4 a, f32x4 b) {
    Frag f;
    #pragma unroll
    for (int j = 0; j < 4; j++) {
        float v = a[j]; __bf16 h = (__bf16)v;
        f.hi[j] = h; f.lo[j] = (__bf16)(v - (float)h);
    }
    #pragma unroll
    for (int j = 0; j < 4; j++) {
        float v = b[j]; __bf16 h = (__bf16)v;
        f.hi[4 + j] = h; f.lo[4 + j] = (__bf16)(v - (float)h);
    }
    return f;
}
__device__ __forceinline__ Frag load_split(const float* p) {
    return make_frag(*(const f32x4*)p, *(const f32x4*)(p + 4));
}
// acc += A*B with hi/lo 3-term product (drops lo*lo ~ 2^-18)
__device__ __forceinline__ f32x4 mm3(Frag a, Frag b, f32x4 acc) {
    acc = mfma16(a.hi, b.hi, acc);
    acc = mfma16(a.hi, b.lo, acc);
    acc = mfma16(a.lo, b.hi, acc);
    return acc;
}

__global__ __launch_bounds__(256, 1)
void dien_fused(const int* __restrict__ u_idx, const int* __restrict__ i_idx,
                const int* __restrict__ seq, const float* __restrict__ item_emb,
                const float* __restrict__ user_bias, const float* __restrict__ item_bias,
                const float* __restrict__ gw_ih, const float* __restrict__ gb_ih,
                const float* __restrict__ gw_hh, const float* __restrict__ gb_hh,
                const float* __restrict__ attn_w, const float* __restrict__ attn_b,
                const float* __restrict__ wr_w, const float* __restrict__ wr_b,
                const float* __restrict__ wz_w, const float* __restrict__ wz_b,
                const float* __restrict__ wh_w, const float* __restrict__ wh_b,
                const float* __restrict__ aux_w, const float* __restrict__ aux_b,
                float* __restrict__ out)
{
    __shared__ int sSeq[16][T_LEN];
    __shared__ __align__(16) float sTP[16][64];
    __shared__ __align__(16) __bf16 sHGhi[16][72], sHGlo[16][72];
    __shared__ __align__(16) __bf16 sHAhi[16][72], sHAlo[16][72];
    __shared__ __align__(16) __bf16 sRHhi[16][72], sRHlo[16][72];
    __shared__ __align__(16) float sParts[16][4];

    const int tid  = threadIdx.x;
    const int wave = tid >> 6;
    const int lane = tid & 63;
    const int c    = lane & 15;       // A-row / C-col index
    const int q    = lane >> 4;       // quad
    const int row0 = blockIdx.x * 16; // batch rows [row0, row0+16)
    const int dglob = wave * 16 + c;  // this lane's output feature d in [0,64)

    // ---- stage seq indices ----
    for (int i = tid; i < 16 * T_LEN; i += 256) {
        int b = i / T_LEN, t = i - b * T_LEN;
        sSeq[b][t] = seq[(row0 + b) * T_LEN + t];
    }

    // ---- fm1 ----
    if (tid < 16) {
        int b = row0 + tid;
        out[b] = user_bias[u_idx[b]] + item_bias[i_idx[b]];
    }

    // ---- target_proj = item_emb[i_idx] @ attn_w^T + attn_b (16x64 fp32) ----
    {
        int b  = tid >> 4;
        int d0 = (tid & 15) * 4;
        const float* erow = item_emb + (long)i_idx[row0 + b] * 64;
        float e[64];
        #pragma unroll
        for (int k4 = 0; k4 < 16; k4++) {
            f32x4 v = *(const f32x4*)(erow + k4 * 4);
            #pragma unroll
            for (int j = 0; j < 4; j++) e[k4 * 4 + j] = v[j];
        }
        #pragma unroll
        for (int dd = 0; dd < 4; dd++) {
            int d = d0 + dd;
            const float* wrow = attn_w + d * 64;
            float s = attn_b[d];
            #pragma unroll
            for (int k4 = 0; k4 < 16; k4++) {
                f32x4 wv = *(const f32x4*)(wrow + k4 * 4);
                #pragma unroll
                for (int j = 0; j < 4; j++) s += e[k4 * 4 + j] * wv[j];
            }
            sTP[b][d] = s;
        }
    }

    // ---- zero h_aug exchange buffers ----
    for (int i = tid; i < 16 * 72; i += 256) {
        ((__bf16*)sHAhi)[i] = (__bf16)0.0f;
        ((__bf16*)sHAlo)[i] = (__bf16)0.0f;
    }
    __syncthreads();

    // ---- register-resident weight B-fragments (hi/lo split) ----
    // B-frag: lane (c,q) holds W[n = wave*16+c][k = s*32 + q*8 + j]
    Frag wih[3][2], whh[3][2];
    #pragma unroll
    for (int g = 0; g < 3; g++) {
        int f = g * 64 + dglob;
        #pragma unroll
        for (int s = 0; s < 2; s++) {
            wih[g][s] = load_split(gw_ih + f * 64 + s * 32 + q * 8);
            whh[g][s] = load_split(gw_hh + f * 64 + s * 32 + q * 8);
        }
    }
    Frag wrx[2], wrh[2], wzx[2], wzh[2], whx[2], whhat[2];
    #pragma unroll
    for (int s = 0; s < 2; s++) {
        const int fo = dglob * 128 + s * 32 + q * 8;
        wrx[s]   = load_split(wr_w + fo);
        wrh[s]   = load_split(wr_w + fo + 64);
        wzx[s]   = load_split(wz_w + fo);
        wzh[s]   = load_split(wz_w + fo + 64);
        whx[s]   = load_split(wh_w + fo);
        whhat[s] = load_split(wh_w + fo + 64);
    }

    // ---- per-lane biases (feature = dglob) ----
    const float bR  = gb_ih[dglob]       + gb_hh[dglob];
    const float bZ  = gb_ih[64 + dglob]  + gb_hh[64 + dglob];
    const float bNX = gb_ih[128 + dglob];
    const float bNH = gb_hh[128 + dglob];
    const float bAR = wr_b[dglob];
    const float bAZ = wz_b[dglob];
    const float bAH = wh_b[dglob];
    const float auxwc = aux_w[dglob];

    float tp_c[4];
    #pragma unroll
    for (int i = 0; i < 4; i++) tp_c[i] = sTP[q * 4 + i][dglob];

    // ---- state ----
    float hg_c[4] = {0.f, 0.f, 0.f, 0.f};
    float ha_c[4] = {0.f, 0.f, 0.f, 0.f};
    Frag hgf[2];
    #pragma unroll
    for (int s = 0; s < 2; s++)
        #pragma unroll
        for (int j = 0; j < 8; j++) { hgf[s].hi[j] = (__bf16)0.f; hgf[s].lo[j] = (__bf16)0.f; }

    // ---- prefetch x for t=0: lane (c,q) covers row sSeq[c][0], k = q*8..+7, 32+q*8..+7
    const float* ep0 = item_emb + (long)sSeq[c][0] * 64 + q * 8;
    f32x4 xa0 = *(const f32x4*)ep0, xa1 = *(const f32x4*)(ep0 + 4);
    f32x4 xb0 = *(const f32x4*)(ep0 + 32), xb1 = *(const f32x4*)(ep0 + 36);

    for (int t = 0; t < T_LEN; t++) {
        Frag xA[2];
        xA[0] = make_frag(xa0, xa1);
        xA[1] = make_frag(xb0, xb1);
        // prefetch t+1
        int tn = (t + 1 < T_LEN) ? t + 1 : t;
        const float* ep = item_emb + (long)sSeq[c][tn] * 64 + q * 8;
        xa0 = *(const f32x4*)ep;  xa1 = *(const f32x4*)(ep + 4);
        xb0 = *(const f32x4*)(ep + 32); xb1 = *(const f32x4*)(ep + 36);

        // h_aug A-frags (written end of prev iter, after barrier2)
        Frag haf[2];
        haf[0].hi = *(const bf16x8*)&sHAhi[c][q * 8];
        haf[1].hi = *(const bf16x8*)&sHAhi[c][32 + q * 8];
        haf[0].lo = *(const bf16x8*)&sHAlo[c][q * 8];
        haf[1].lo = *(const bf16x8*)&sHAlo[c][32 + q * 8];

        // ---- projections ----
        f32x4 accR = {0.f, 0.f, 0.f, 0.f};
        accR = mm3(xA[0], wih[0][0], accR); accR = mm3(xA[1], wih[0][1], accR);
        accR = mm3(hgf[0], whh[0][0], accR); accR = mm3(hgf[1], whh[0][1], accR);
        f32x4 accZ = {0.f, 0.f, 0.f, 0.f};
        accZ = mm3(xA[0], wih[1][0], accZ); accZ = mm3(xA[1], wih[1][1], accZ);
        accZ = mm3(hgf[0], whh[1][0], accZ); accZ = mm3(hgf[1], whh[1][1], accZ);
        f32x4 accNX = {0.f, 0.f, 0.f, 0.f};
        accNX = mm3(xA[0], wih[2][0], accNX); accNX = mm3(xA[1], wih[2][1], accNX);
        f32x4 accNH = {0.f, 0.f, 0.f, 0.f};
        accNH = mm3(hgf[0], whh[2][0], accNH); accNH = mm3(hgf[1], whh[2][1], accNH);

        f32x4 accAR = {0.f, 0.f, 0.f, 0.f};
        accAR = mm3(xA[0], wrx[0], accAR); accAR = mm3(xA[1], wrx[1], accAR);
        accAR = mm3(haf[0], wrh[0], accAR); accAR = mm3(haf[1], wrh[1], accAR);
        f32x4 accAZ = {0.f, 0.f, 0.f, 0.f};
        accAZ = mm3(xA[0], wzx[0], accAZ); accAZ = mm3(xA[1], wzx[1], accAZ);
        accAZ = mm3(haf[0], wzh[0], accAZ); accAZ = mm3(haf[1], wzh[1], accAZ);
        f32x4 accAH = {0.f, 0.f, 0.f, 0.f};
        accAH = mm3(xA[0], whx[0], accAH); accAH = mm3(xA[1], whx[1], accAH);

        // ---- GRU gating -> h_gru_t; attn-score partials ----
        float pr[4];
        #pragma unroll
        for (int i = 0; i < 4; i++) {
            float r = sigf(accR[i] + bR);
            float z = sigf(accZ[i] + bZ);
            float n = tanh_fast(accNX[i] + bNX + r * (accNH[i] + bNH));
            float hn = (1.0f - z) * n + z * hg_c[i];
            hg_c[i] = hn;
            __bf16 hi = (__bf16)hn;
            int rr = q * 4 + i;
            sHGhi[rr][dglob] = hi;
            sHGlo[rr][dglob] = (__bf16)(hn - (float)hi);
            pr[i] = hn * tp_c[i];
        }
        #pragma unroll
        for (int m = 1; m < 16; m <<= 1) {
            #pragma unroll
            for (int i = 0; i < 4; i++) pr[i] += __shfl_xor(pr[i], m, 64);
        }
        if (c == 0) {
            #pragma unroll
            for (int i = 0; i < 4; i++) sParts[q * 4 + i][wave] = pr[i];
        }

        // ---- AUGRU r,z gating; rh = r*h_aug ----
        float z_c[4];
        #pragma unroll
        for (int i = 0; i < 4; i++) {
            float r = sigf(accAR[i] + bAR);
            z_c[i]  = sigf(accAZ[i] + bAZ);
            float rh = r * ha_c[i];
            __bf16 hi = (__bf16)rh;
            int rr = q * 4 + i;
            sRHhi[rr][dglob] = hi;
            sRHlo[rr][dglob] = (__bf16)(rh - (float)hi);
        }

        __syncthreads();  // barrier 1

        hgf[0].hi = *(const bf16x8*)&sHGhi[c][q * 8];
        hgf[1].hi = *(const bf16x8*)&sHGhi[c][32 + q * 8];
        hgf[0].lo = *(const bf16x8*)&sHGlo[c][q * 8];
        hgf[1].lo = *(const bf16x8*)&sHGlo[c][32 + q * 8];
        Frag rhf[2];
        rhf[0].hi = *(const bf16x8*)&sRHhi[c][q * 8];
        rhf[1].hi = *(const bf16x8*)&sRHhi[c][32 + q * 8];
        rhf[0].lo = *(const bf16x8*)&sRHlo[c][q * 8];
        rhf[1].lo = *(const bf16x8*)&sRHlo[c][32 + q * 8];

        accAH = mm3(rhf[0], whhat[0], accAH);
        accAH = mm3(rhf[1], whhat[1], accAH);

        #pragma unroll
        for (int i = 0; i < 4; i++) {
            int rr = q * 4 + i;
            float a = sigf(sParts[rr][0] + sParts[rr][1] + sParts[rr][2] + sParts[rr][3]);
            float zz = a * z_c[i];
            float hh = tanh_fast(accAH[i] + bAH);
            float hv = (1.0f - zz) * ha_c[i] + zz * hh;
            ha_c[i] = hv;
            __bf16 hi = (__bf16)hv;
            sHAhi[rr][dglob] = hi;
            sHAlo[rr][dglob] = (__bf16)(hv - (float)hi);
        }

        __syncthreads();  // barrier 2
    }

    // ---- attn_vec ----
    #pragma unroll
    for (int i = 0; i < 4; i++) {
        int b = row0 + q * 4 + i;
        out[NB + b * 64 + dglob] = ha_c[i];
    }

    // ---- aux_logits ----
    float pa[4];
    #pragma unroll
    for (int i = 0; i < 4; i++) pa[i] = hg_c[i] * auxwc;
    #pragma unroll
    for (int m = 1; m < 16; m <<= 1) {
        #pragma unroll
        for (int i = 0; i < 4; i++) pa[i] += __shfl_xor(pa[i], m, 64);
    }
    if (c == 0) {
        #pragma unroll
        for (int i = 0; i < 4; i++) sParts[q * 4 + i][wave] = pa[i];
    }
    __syncthreads();
    if (tid < 16) {
        out[NB + NB * 64 + row0 + tid] =
            sParts[tid][0] + sParts[tid][1] + sParts[tid][2] + sParts[tid][3] + aux_b[0];
    }
}

extern "C" void kernel_launch(void* const* d_in, const int* in_sizes, int n_in,
                              void* d_out, int out_size, void* d_ws, size_t ws_size,
                              hipStream_t stream) {
    dien_fused<<<dim3(256), dim3(256), 0, stream>>>(
        (const int*)d_in[0],      // u_idx
        (const int*)d_in[1],      // i_idx
        (const int*)d_in[2],      // seq
        (const float*)d_in[3],    // item_emb
        (const float*)d_in[4],    // user_bias
        (const float*)d_in[5],    // item_bias
        (const float*)d_in[6],    // gru_w_ih
        (const float*)d_in[7],    // gru_b_ih
        (const float*)d_in[8],    // gru_w_hh
        (const float*)d_in[9],    // gru_b_hh
        (const float*)d_in[10],   // attn_w
        (const float*)d_in[11],   // attn_b
        (const float*)d_in[12],   // wr_w
        (const float*)d_in[13],   // wr_b
        (const float*)d_in[14],   // wz_w
        (const float*)d_in[15],   // wz_b
        (const float*)d_in[16],   // wh_w
        (const float*)d_in[17],   // wh_b
        (const float*)d_in[18],   // aux_w
        (const float*)d_in[19],   // aux_b
        (float*)d_out);
}